// Round 8
// baseline (1168.482 us; speedup 1.0000x reference)
//
#include <hip/hip_runtime.h>
#include <cstdint>

#define NVEH  4096
#define NT    1024
#define INW   12
#define UNITS 20

typedef float f32x2 __attribute__((ext_vector_type(2)));

#define PIN(v)  asm volatile("" : "+v"(v))

// z.lo += W.lo * op.lo ; z.hi += W.hi * op.lo   (broadcast LOW of operand)
#define PKFMA_LO(acc, w, s2) \
    asm("v_pk_fma_f32 %0, %1, %2, %0 op_sel:[0,0,0] op_sel_hi:[1,0,1]" \
        : "+v"(acc) : "v"(w), "v"(s2))
// z.lo += W.lo * op.hi ; z.hi += W.hi * op.hi   (broadcast HIGH of operand)
#define PKFMA_HI(acc, w, s2) \
    asm("v_pk_fma_f32 %0, %1, %2, %0 op_sel:[0,1,0] op_sel_hi:[1,1,1]" \
        : "+v"(acc) : "v"(w), "v"(s2))
// elementwise packed fma
#define PKFMA(acc, a, b) \
    asm("v_pk_fma_f32 %0, %1, %2, %0" : "+v"(acc) : "v"(a), "v"(b))

__device__ __forceinline__ float fexp2(float x) { return __builtin_amdgcn_exp2f(x); }
__device__ __forceinline__ float frcp(float x)  { return __builtin_amdgcn_rcpf(x); }

__device__ __forceinline__ f32x2 shfl2(f32x2 v, int src) {
    f32x2 r;
    r[0] = __shfl(v[0], src, 64);
    r[1] = __shfl(v[1], src, 64);
    return r;
}

// async global -> LDS, 16B per active lane, dest = uniform base + lane*16
__device__ __forceinline__ void gload_lds16(const float* g, float* l) {
    __builtin_amdgcn_global_load_lds(
        (const __attribute__((address_space(1))) unsigned int*)g,
        (__attribute__((address_space(3))) unsigned int*)l,
        16, 0, 0);
}

// 1 vehicle per wave; 60 lanes = 20 units x 3 slices. Each lane computes 1/3
// of the z dot for its unit's gate-pairs; __shfl(+20,+40) reduces slices into
// part-0 lanes. Per-wave VALU pipe time ~620 -> ~260 cyc/step; 4096 waves ->
// 4 waves/SIMD so residual latency overlaps across waves.
__global__ __attribute__((amdgpu_waves_per_eu(4, 4))) __launch_bounds__(64)
void rnncf_kernel(const float* __restrict__ x,          // (NVEH, NT, 12)
                  const float* __restrict__ init_state, // (NVEH, 2)
                  const float* __restrict__ hs,         // (2, NVEH, 20)
                  const float* __restrict__ K,          // (12, 80)
                  const float* __restrict__ R,          // (20, 80)
                  const float* __restrict__ bias,       // (80)
                  const float* __restrict__ W2,         // (20, 10)
                  const float* __restrict__ b2,         // (10)
                  const float* __restrict__ Wlc,        // (10, 3)
                  const float* __restrict__ blc,        // (3)
                  const float* __restrict__ W1,         // (10, 1)
                  const float* __restrict__ b1,         // (1)
                  float* __restrict__ out)
{
    const int lane = threadIdx.x;
    const bool realp = (lane < 60);
    const int part = realp ? (lane / 20) : 2;   // slice 0..2; lanes 60-63 ride p2
    const int u    = lane % 20;                  // unit index
    const int veh  = blockIdx.x;                 // grid == NVEH exactly

    __shared__ __align__(16) float xf[8][12];    // x FIFO, 48B/slot
    __shared__ __align__(16) float hb[20];       // h buffer
    __shared__ __align__(16) float x2b[12];      // x2 buffer (10 + pad)
    __shared__ __align__(16) float wlcl[3][12];  // Wlc column-major pairs

    // slice geometry: h-pairs {0-3 | 4-7 | 8-9}, x-pairs {0-1 | 2-3 | 4-5}
    const int hbase = (part == 0) ? 0 : (part == 1) ? 4 : 8;
    const int xbase = part * 2;

    // ---- per-lane sliced weights (gate exp2 scale + input coefs folded) ----
    const float L2E = 1.4426950408889634f;
    const float sI = -L2E, sF = -L2E, sG = 2.0f * L2E, sO = -L2E;
    f32x2 We01[6], Wo01[6], We23[6], Wo23[6], W2s[4];
#pragma unroll
    for (int j = 0; j < 4; ++j) {               // h operand-pairs
        const bool ok = realp && !(part == 2 && j >= 2);
        const int hp = ok ? (hbase + j) : 0;
        const int r0 = (2 * hp) * 80, r1 = (2 * hp + 1) * 80;
        const float m = ok ? 1.0f : 0.0f;
        We01[j][0] = m * sI * R[r0 + u];      We01[j][1] = m * sF * R[r0 + 20 + u];
        Wo01[j][0] = m * sI * R[r1 + u];      Wo01[j][1] = m * sF * R[r1 + 20 + u];
        We23[j][0] = m * sG * R[r0 + 40 + u]; We23[j][1] = m * sO * R[r0 + 60 + u];
        Wo23[j][0] = m * sG * R[r1 + 40 + u]; Wo23[j][1] = m * sO * R[r1 + 60 + u];
        const int mh_ = (u < 10) ? u : 9;
        W2s[j][0] = m * W2[(2 * hp) * 10 + mh_];
        W2s[j][1] = m * W2[(2 * hp + 1) * 10 + mh_];
    }
#pragma unroll
    for (int j = 4; j < 6; ++j) {               // x operand-pairs (folded K)
        const int xp = xbase + (j - 4);
        const int k0 = 2 * xp, k1 = k0 + 1;
        const float c0 = (k0 < 3) ? 0.01f : (k0 < 6) ? -0.01f : 0.025f;
        const float c1 = (k1 < 3) ? 0.01f : (k1 < 6) ? -0.01f : 0.025f;
        const float m = realp ? 1.0f : 0.0f;
        We01[j][0] = m * sI * c0 * K[k0 * 80 + u];      We01[j][1] = m * sF * c0 * K[k0 * 80 + 20 + u];
        Wo01[j][0] = m * sI * c1 * K[k1 * 80 + u];      Wo01[j][1] = m * sF * c1 * K[k1 * 80 + 20 + u];
        We23[j][0] = m * sG * c0 * K[k0 * 80 + 40 + u]; We23[j][1] = m * sO * c0 * K[k0 * 80 + 60 + u];
        Wo23[j][0] = m * sG * c1 * K[k1 * 80 + 40 + u]; Wo23[j][1] = m * sO * c1 * K[k1 * 80 + 60 + u];
    }
    // bias + pos-coupling term live only in part-0 partials
    f32x2 bzL01, bzL23, kd01, kd23;
    bzL01[0]=bzL01[1]=bzL23[0]=bzL23[1]=0.0f;
    kd01[0]=kd01[1]=kd23[0]=kd23[1]=0.0f;
    if (lane < 20) {
        bzL01[0] = sI * bias[u];      bzL01[1] = sF * bias[20 + u];
        bzL23[0] = sG * bias[40 + u]; bzL23[1] = sO * bias[60 + u];
        float aI = 0, aF = 0, aG = 0, aO = 0;
        for (int k = 0; k < 6; ++k) {
            float sgn = (k < 3) ? -0.01f : 0.01f;
            aI += sgn * K[k * 80 + u];
            aF += sgn * K[k * 80 + 20 + u];
            aG += sgn * K[k * 80 + 40 + u];
            aO += sgn * K[k * 80 + 60 + u];
        }
        kd01[0] = sI * aI; kd01[1] = sF * aF;
        kd23[0] = sG * aG; kd23[1] = sO * aO;
    }
    const int mh = (u < 10) ? u : 9;
    const float b2L  = (lane < 20) ? b2[mh] : 0.0f;
    const float blcs = blc[(u < 3) ? u : 0];
#pragma unroll
    for (int j = 0; j < 6; ++j) { PIN(We01[j]); PIN(Wo01[j]); PIN(We23[j]); PIN(Wo23[j]); }
#pragma unroll
    for (int j = 0; j < 4; ++j) PIN(W2s[j]);
    PIN(bzL01); PIN(bzL23); PIN(kd01); PIN(kd23);

    // Wlc -> LDS table (read by lanes 0..2 only in phase A)
    for (int idx = lane; idx < 36; idx += 64) {
        int j = idx / 12, m = idx % 12;
        wlcl[j][m] = (m < 10) ? Wlc[m * 3 + j] : 0.0f;
    }

    // ---- state ----
    float pos  = init_state[veh * 2 + 0];
    float spd  = init_state[veh * 2 + 1];
    float c    = hs[(size_t)NVEH * UNITS + (size_t)veh * UNITS + u];
    float hnew = hs[(size_t)veh * UNITS + u];
    if (lane < 20) hb[u] = hnew;
    __builtin_amdgcn_wave_barrier();

    // ---- x FIFO: lanes 0..2 stage 16B/step ----
    const bool stgL = (lane < 3);
    const float* sgp = x + (size_t)veh * NT * INW + lane * 4;
    if (stgL) {
#pragma unroll
        for (int t0 = 0; t0 < 8; ++t0)
            gload_lds16(sgp + (size_t)t0 * INW, &xf[t0][0]);
    }

    // operand addresses (per-slice, data-driven; uniform code)
    const float* ha0p = &hb[(part == 0) ? 0 : (part == 1) ? 8 : 16];
    const float* ha1p = &hb[(part == 0) ? 4 : (part == 1) ? 12 : 0];
    const int xo = part * 4;
    const int sA = (lane + 20) & 63, sB = (lane + 40) & 63;

    float* trajp = out + (size_t)veh * NT;
    float* lcp   = out + (size_t)NVEH * NT + (size_t)veh * NT * 3;

    // ---- prologue: partials for t=0 (h0 + x slot0) ----
    asm volatile("s_waitcnt vmcnt(7)" ::: "memory");
    f32x2 zn01, zn23, op[6];
    {
        float4 r0 = *(const float4*)ha0p;
        float4 r1 = *(const float4*)ha1p;
        float4 r2 = *(const float4*)&xf[0][xo];
        op[0][0]=r0.x; op[0][1]=r0.y; op[1][0]=r0.z; op[1][1]=r0.w;
        op[2][0]=r1.x; op[2][1]=r1.y; op[3][0]=r1.z; op[3][1]=r1.w;
        op[4][0]=r2.x; op[4][1]=r2.y; op[5][0]=r2.z; op[5][1]=r2.w;
        zn01 = bzL01; zn23 = bzL23;
#pragma unroll
        for (int j = 0; j < 6; ++j) {
            PKFMA_LO(zn01, We01[j], op[j]);
            PKFMA_LO(zn23, We23[j], op[j]);
            PKFMA_HI(zn01, Wo01[j], op[j]);
            PKFMA_HI(zn23, Wo23[j], op[j]);
        }
    }
    f32x2 x2p[5];
#pragma unroll
    for (int q = 0; q < 5; ++q) { x2p[q][0] = 0.0f; x2p[q][1] = 0.0f; }
    f32x2 posp;

    for (int tb = 0; tb < NT; tb += 4) {
        // body reads x slots tb+1..tb+4; keep 3 newest loads in flight
        asm volatile("s_waitcnt vmcnt(3)" ::: "memory");

#pragma unroll
        for (int j4 = 0; j4 < 4; ++j4) {
            const int t = tb + j4;

            // ---- A: head finish acc(t-1) -> spd_t; pos update ----
            if (t > 0) {
                float a0 = b1[0], a1 = 0.0f;
#pragma unroll
                for (int m = 0; m < 5; ++m) {
                    a0 = fmaf(x2p[m][0], W1[2*m],   a0);
                    a1 = fmaf(x2p[m][1], W1[2*m+1], a1);
                }
                spd = fmaf(0.1f, fmaf(10.0f, a0 + a1, -6.0f), spd);
                if (lane < 3) {
                    float4 wa = *(const float4*)&wlcl[lane][0];
                    float4 wb = *(const float4*)&wlcl[lane][4];
                    float2 wc = *(const float2*)&wlcl[lane][8];
                    f32x2 w0, w1_, w2_, w3, w4;
                    w0[0]=wa.x; w0[1]=wa.y; w1_[0]=wa.z; w1_[1]=wa.w;
                    w2_[0]=wb.x; w2_[1]=wb.y; w3[0]=wb.z; w3[1]=wb.w;
                    w4[0]=wc.x; w4[1]=wc.y;
                    f32x2 lc2; lc2[0] = blcs; lc2[1] = 0.0f;
                    PKFMA(lc2, x2p[0], w0); PKFMA(lc2, x2p[1], w1_);
                    PKFMA(lc2, x2p[2], w2_); PKFMA(lc2, x2p[3], w3);
                    PKFMA(lc2, x2p[4], w4);
                    lcp[(t - 1) * 3 + lane] = lc2[0] + lc2[1];
                }
            }
            const float pold = pos;
            pos = fmaf(0.1f, spd, pold);
            if (lane == 0) trajp[t] = pos;
            posp[0] = pold; posp[1] = pold;

            // ---- B: reduce slice partials -> z (valid in part-0 lanes) ----
            f32x2 z01 = (zn01 + shfl2(zn01, sA)) + shfl2(zn01, sB);
            f32x2 z23 = (zn23 + shfl2(zn23, sA)) + shfl2(zn23, sB);
            PKFMA(z01, kd01, posp);      // kd==0 off part-0
            PKFMA(z23, kd23, posp);

            // ---- C: cell update (junk on lanes>=20, never written) ----
            float ig = frcp(1.0f + fexp2(z01[0]));
            float fg = frcp(1.0f + fexp2(z01[1]));
            float gg = 1.0f - 2.0f * frcp(fexp2(z23[0]) + 1.0f);
            float og = frcp(1.0f + fexp2(z23[1]));
            c = fmaf(fg, c, ig * gg);
            float th = 1.0f - 2.0f * frcp(fexp2(2.8853900817779268f * c) + 1.0f);
            hnew = og * th;

            // ---- D: publish h_t, fetch operand slices (h_t + x_{t+1}) ----
            if (lane < 20) hb[u] = hnew;
            {
                const int sl = (t + 1) & 7;
                float4 r0 = *(const float4*)ha0p;
                float4 r1 = *(const float4*)ha1p;
                float4 r2 = *(const float4*)&xf[sl][xo];
                op[0][0]=r0.x; op[0][1]=r0.y; op[1][0]=r0.z; op[1][1]=r0.w;
                op[2][0]=r1.x; op[2][1]=r1.y; op[3][0]=r1.z; op[3][1]=r1.w;
                op[4][0]=r2.x; op[4][1]=r2.y; op[5][0]=r2.z; op[5][1]=r2.w;
            }

            // ---- E: split head xm = relu(h.W2[:,mh]+b2) + x2 exchange ----
            f32x2 xm2; xm2[0] = b2L; xm2[1] = 0.0f;
            PKFMA(xm2, op[0], W2s[0]); PKFMA(xm2, op[1], W2s[1]);
            PKFMA(xm2, op[2], W2s[2]); PKFMA(xm2, op[3], W2s[3]);
            xm2 = (xm2 + shfl2(xm2, sA)) + shfl2(xm2, sB);
            float xmv = fmaxf(xm2[0] + xm2[1], 0.0f);
            if (lane < 10) x2b[lane] = xmv;
            {
                float4 a = *(const float4*)&x2b[0];
                float4 b4 = *(const float4*)&x2b[4];
                float2 e = *(const float2*)&x2b[8];
                x2p[0][0]=a.x;  x2p[0][1]=a.y;  x2p[1][0]=a.z;  x2p[1][1]=a.w;
                x2p[2][0]=b4.x; x2p[2][1]=b4.y; x2p[3][0]=b4.z; x2p[3][1]=b4.w;
                x2p[4][0]=e.x;  x2p[4][1]=e.y;
            }

            // ---- F: slice partials for t+1 (24 pk, the whole dot) ----
            zn01 = bzL01; zn23 = bzL23;
#pragma unroll
            for (int j = 0; j < 6; ++j) {
                PKFMA_LO(zn01, We01[j], op[j]);
                PKFMA_LO(zn23, We23[j], op[j]);
                PKFMA_HI(zn01, Wo01[j], op[j]);
                PKFMA_HI(zn23, Wo23[j], op[j]);
            }
        }

        // stage x(tb+8..tb+11) into the slots just consumed
        if (stgL) {
#pragma unroll
            for (int j = 0; j < 4; ++j) {
                int tt = tb + 8 + j; if (tt > NT - 1) tt = NT - 1;
                gload_lds16(sgp + (size_t)tt * INW, &xf[(tb + j) & 7][0]);
            }
        }
    }

    // ---- epilogue: finish head for step NT-1 ----
    {
        float a0 = b1[0], a1 = 0.0f;
#pragma unroll
        for (int m = 0; m < 5; ++m) {
            a0 = fmaf(x2p[m][0], W1[2*m],   a0);
            a1 = fmaf(x2p[m][1], W1[2*m+1], a1);
        }
        spd = fmaf(0.1f, fmaf(10.0f, a0 + a1, -6.0f), spd);
        if (lane < 3) {
            float4 wa = *(const float4*)&wlcl[lane][0];
            float4 wb = *(const float4*)&wlcl[lane][4];
            float2 wc = *(const float2*)&wlcl[lane][8];
            f32x2 w0, w1_, w2_, w3, w4;
            w0[0]=wa.x; w0[1]=wa.y; w1_[0]=wa.z; w1_[1]=wa.w;
            w2_[0]=wb.x; w2_[1]=wb.y; w3[0]=wb.z; w3[1]=wb.w;
            w4[0]=wc.x; w4[1]=wc.y;
            f32x2 lc2; lc2[0] = blcs; lc2[1] = 0.0f;
            PKFMA(lc2, x2p[0], w0); PKFMA(lc2, x2p[1], w1_);
            PKFMA(lc2, x2p[2], w2_); PKFMA(lc2, x2p[3], w3);
            PKFMA(lc2, x2p[4], w4);
            lcp[(NT - 1) * 3 + lane] = lc2[0] + lc2[1];
        }
    }

    {
        float* spdf = out + (size_t)NVEH * NT * 4;
        float* hf   = spdf + NVEH;
        float* cf   = hf + (size_t)NVEH * UNITS;
        if (lane == 0) spdf[veh] = spd;
        if (lane < 20) {
            hf[(size_t)veh * UNITS + u] = hnew;
            cf[(size_t)veh * UNITS + u] = c;
        }
    }
}

extern "C" void kernel_launch(void* const* d_in, const int* in_sizes, int n_in,
                              void* d_out, int out_size, void* d_ws, size_t ws_size,
                              hipStream_t stream) {
    const float* x    = (const float*)d_in[0];
    const float* st0  = (const float*)d_in[1];
    const float* hs   = (const float*)d_in[2];
    const float* K    = (const float*)d_in[3];
    const float* R    = (const float*)d_in[4];
    const float* bias = (const float*)d_in[5];
    const float* W2   = (const float*)d_in[6];
    const float* b2   = (const float*)d_in[7];
    const float* Wlc  = (const float*)d_in[8];
    const float* blc  = (const float*)d_in[9];
    const float* W1   = (const float*)d_in[10];
    const float* b1   = (const float*)d_in[11];
    float* out = (float*)d_out;

    dim3 grid(NVEH);    // 4096 blocks, 1 vehicle each, 3-way sliced dots
    dim3 block(64);
    hipLaunchKernelGGL(rnncf_kernel, grid, block, 0, stream,
                       x, st0, hs, K, R, bias, W2, b2, Wlc, blc, W1, b1, out);
}

// Round 9
// 1004.920 us; speedup vs baseline: 1.1628x; 1.1628x over previous
//
#include <hip/hip_runtime.h>
#include <cstdint>

#define NVEH  4096
#define NT    1024
#define INW   12
#define UNITS 20

typedef float f32x2 __attribute__((ext_vector_type(2)));

#define PIN(v)  asm volatile("" : "+v"(v))

// Packed dual-FMA (VOP3P): acc.lo += w.lo * s, acc.hi += w.hi * s
// where s is the LOW half of the pair operand (op_sel_hi[src1]=0 broadcasts lo).
#define PKFMA_LO(acc, w, s2) \
    asm("v_pk_fma_f32 %0, %1, %2, %0 op_sel:[0,0,0] op_sel_hi:[1,0,1]" \
        : "+v"(acc) : "v"(w), "v"(s2))
// Same but broadcasting the HIGH half of the pair operand.
#define PKFMA_HI(acc, w, s2) \
    asm("v_pk_fma_f32 %0, %1, %2, %0 op_sel:[0,1,0] op_sel_hi:[1,1,1]" \
        : "+v"(acc) : "v"(w), "v"(s2))
// Packed mul, broadcasting low half of src1 (chain-head init, saves movs)
#define PKMUL_LO(dst, w, s2) \
    asm("v_pk_mul_f32 %0, %1, %2 op_sel:[0,0] op_sel_hi:[1,0]" \
        : "=v"(dst) : "v"(w), "v"(s2))
// Full element-wise packed fma: acc += a * b (both halves independent)
#define PKFMA(acc, a, b) \
    asm("v_pk_fma_f32 %0, %1, %2, %0" : "+v"(acc) : "v"(a), "v"(b))

__device__ __forceinline__ float fexp2(float x) { return __builtin_amdgcn_exp2f(x); }
__device__ __forceinline__ float frcp(float x)  { return __builtin_amdgcn_rcpf(x); }

// r7 rotated chassis; x path moved LDS->registers (per-lane loads, L1
// broadcast), no manual vmcnt anywhere (compiler inserts exact waits and
// never waits on store-acks), traj stores buffered x4.
__global__ __attribute__((amdgpu_waves_per_eu(2, 2))) __launch_bounds__(64)
void rnncf_kernel(const float* __restrict__ x,          // (NVEH, NT, 12)
                  const float* __restrict__ init_state, // (NVEH, 2)
                  const float* __restrict__ hs,         // (2, NVEH, 20)
                  const float* __restrict__ K,          // (12, 80)
                  const float* __restrict__ R,          // (20, 80)
                  const float* __restrict__ bias,       // (80)
                  const float* __restrict__ W2,         // (20, 10)
                  const float* __restrict__ b2,         // (10)
                  const float* __restrict__ Wlc,        // (10, 3)
                  const float* __restrict__ blc,        // (3)
                  const float* __restrict__ W1,         // (10, 1)
                  const float* __restrict__ b1,         // (1)
                  float* __restrict__ out)
{
    const int lane = threadIdx.x;
    const int grp  = lane / 20;     // 0..2 = vehicle slot, 3 = idle lanes 60..63
    const int sub  = lane % 20;     // unit index / head index
    const int veh  = blockIdx.x * 3 + grp;
    const bool active = (grp < 3) && (veh < NVEH);
    const int vs = active ? veh : 0;

    __shared__ __align__(16) float h_lds[4][20];
    __shared__ __align__(16) float x2_lds[4][12];

    // ---- folded weights: input-transform coefs AND gate exp2 scale baked in
    // (r4/r7-verified math). zKx = bz + sum K''*x_raw is pos-free; the pos
    // term is a single kd*pos FMA at join time.
    const float L2E = 1.4426950408889634f;
    const float sI = -L2E, sF = -L2E, sG = 2.0f * L2E, sO = -L2E;
    f32x2 K01[12], K23[12], R01[20], R23[20], bz01, bz23, kd01, kd23;
#pragma unroll
    for (int k = 0; k < 12; ++k) {
        float ck = (k < 3) ? 0.01f : (k < 6) ? -0.01f : 0.025f;
        K01[k][0] = sI * ck * K[k * 80 + sub];
        K01[k][1] = sF * ck * K[k * 80 + 20 + sub];
        K23[k][0] = sG * ck * K[k * 80 + 40 + sub];
        K23[k][1] = sO * ck * K[k * 80 + 60 + sub];
    }
    {
        float aI = 0, aF = 0, aG = 0, aO = 0;
        for (int k = 0; k < 6; ++k) {
            float sgn = (k < 3) ? -0.01f : 0.01f;
            aI += sgn * K[k * 80 + sub];
            aF += sgn * K[k * 80 + 20 + sub];
            aG += sgn * K[k * 80 + 40 + sub];
            aO += sgn * K[k * 80 + 60 + sub];
        }
        kd01[0] = sI * aI; kd01[1] = sF * aF;
        kd23[0] = sG * aG; kd23[1] = sO * aO;
    }
    bz01[0] = sI * bias[sub];      bz01[1] = sF * bias[20 + sub];
    bz23[0] = sG * bias[40 + sub]; bz23[1] = sO * bias[60 + sub];
#pragma unroll
    for (int k = 0; k < 20; ++k) {
        R01[k][0] = sI * R[k * 80 + sub];      R01[k][1] = sF * R[k * 80 + 20 + sub];
        R23[k][0] = sG * R[k * 80 + 40 + sub]; R23[k][1] = sO * R[k * 80 + 60 + sub];
    }
    const int mh = (sub < 10) ? sub : 9;
    f32x2 W2p[10];
#pragma unroll
    for (int u = 0; u < 10; ++u) {
        W2p[u][0] = W2[(2 * u) * 10 + mh];
        W2p[u][1] = W2[(2 * u + 1) * 10 + mh];
    }
    float b2s = b2[mh];
    const int jl = (sub < 3) ? sub : 0;
    f32x2 Wlcp[5];
#pragma unroll
    for (int m = 0; m < 5; ++m) {
        Wlcp[m][0] = Wlc[(2 * m) * 3 + jl];
        Wlcp[m][1] = Wlc[(2 * m + 1) * 3 + jl];
    }
    float blcs = blc[jl];
    PIN(bz01); PIN(bz23); PIN(kd01); PIN(kd23);
#pragma unroll
    for (int k = 0; k < 12; ++k) { PIN(K01[k]); PIN(K23[k]); }
#pragma unroll
    for (int k = 0; k < 20; ++k) { PIN(R01[k]); PIN(R23[k]); }
#pragma unroll
    for (int u = 0; u < 10; ++u) PIN(W2p[u]);
#pragma unroll
    for (int m = 0; m < 5; ++m) PIN(Wlcp[m]);
    PIN(b2s); PIN(blcs);

    // ---- state ----
    float pos = init_state[vs * 2 + 0];
    float spd = init_state[vs * 2 + 1];
    float c   = hs[(size_t)NVEH * UNITS + (size_t)vs * UNITS + sub];
    float hnew = hs[(size_t)vs * UNITS + sub];

    // ---- initial h exchange ----
    h_lds[grp][sub] = hnew;
    __builtin_amdgcn_wave_barrier();
    f32x2 hrp[10];
#pragma unroll
    for (int q = 0; q < 5; ++q) {
        float4 v = ((const float4*)&h_lds[grp][0])[q];
        hrp[2*q][0]   = v.x; hrp[2*q][1]   = v.y;
        hrp[2*q+1][0] = v.z; hrp[2*q+1][1] = v.w;
    }
    __builtin_amdgcn_wave_barrier();

    // ---- x register prefetch: every lane loads its group's row directly.
    // All 20 lanes of a group issue identical addresses -> L1 broadcast.
    const float4* xg = (const float4*)(x + (size_t)vs * NT * INW); // 3 float4/step
    float4 xq[2][3];                    // slot (t+1)&1 holds x_{t+1}
#pragma unroll
    for (int q = 0; q < 3; ++q) {
        xq[1][q] = xg[1 * 3 + q];       // x_1
        xq[0][q] = xg[2 * 3 + q];       // x_2
    }

    // ---- prologue: zKx(0) from x_0, zA/zB(0) from h0 ----
    f32x2 zKx01, zKx23, zA01, zA23, zB01, zB23;
    {
        float4 u0 = xg[0], u1 = xg[1], u2 = xg[2];
        f32x2 xp[6];
        xp[0][0]=u0.x; xp[0][1]=u0.y; xp[1][0]=u0.z; xp[1][1]=u0.w;
        xp[2][0]=u1.x; xp[2][1]=u1.y; xp[3][0]=u1.z; xp[3][1]=u1.w;
        xp[4][0]=u2.x; xp[4][1]=u2.y; xp[5][0]=u2.z; xp[5][1]=u2.w;
        zKx01 = bz01; zKx23 = bz23;
#pragma unroll
        for (int q = 0; q < 6; ++q) {
            PKFMA_LO(zKx01, K01[2*q],   xp[q]);
            PKFMA_LO(zKx23, K23[2*q],   xp[q]);
            PKFMA_HI(zKx01, K01[2*q+1], xp[q]);
            PKFMA_HI(zKx23, K23[2*q+1], xp[q]);
        }
    }
    PKMUL_LO(zA01, R01[0], hrp[0]);
    PKMUL_LO(zA23, R23[0], hrp[0]);
    PKFMA_HI(zA01, R01[1], hrp[0]);
    PKFMA_HI(zA23, R23[1], hrp[0]);
#pragma unroll
    for (int q = 1; q < 5; ++q) {
        PKFMA_LO(zA01, R01[2*q],   hrp[q]);
        PKFMA_LO(zA23, R23[2*q],   hrp[q]);
        PKFMA_HI(zA01, R01[2*q+1], hrp[q]);
        PKFMA_HI(zA23, R23[2*q+1], hrp[q]);
    }
    PKMUL_LO(zB01, R01[10], hrp[5]);
    PKMUL_LO(zB23, R23[10], hrp[5]);
    PKFMA_HI(zB01, R01[11], hrp[5]);
    PKFMA_HI(zB23, R23[11], hrp[5]);
#pragma unroll
    for (int q = 6; q < 10; ++q) {
        PKFMA_LO(zB01, R01[2*q],   hrp[q]);
        PKFMA_LO(zB23, R23[2*q],   hrp[q]);
        PKFMA_HI(zB01, R01[2*q+1], hrp[q]);
        PKFMA_HI(zB23, R23[2*q+1], hrp[q]);
    }

    f32x2 x2p[5];          // x2(t-1), carried; step 0 guarded
#pragma unroll
    for (int q = 0; q < 5; ++q) { x2p[q][0] = 0.0f; x2p[q][1] = 0.0f; }
    f32x2 posp; posp[0] = pos; posp[1] = 0.0f;

    float* trajp = out + (size_t)vs * NT;
    float* lcp   = out + (size_t)NVEH * NT + (size_t)vs * NT * 3;
    float tj0, tj1, tj2, tj3;

    for (int tb = 0; tb < NT; tb += 4) {
#pragma unroll
        for (int j = 0; j < 4; ++j) {
            const int t = tb + j;

            // ---- A: head finish acc(t-1)->spd_t; pos update ----
            if (t > 0) {
                float a0 = b1[0], a1 = 0.0f;
#pragma unroll
                for (int m = 0; m < 5; ++m) {
                    a0 = fmaf(x2p[m][0], W1[2*m],   a0);
                    a1 = fmaf(x2p[m][1], W1[2*m+1], a1);
                }
                float accr = a0 + a1;
                spd = fmaf(0.1f, fmaf(10.0f, accr, -6.0f), spd);
                if (active && sub < 3) {
                    f32x2 lc2; lc2[0] = blcs; lc2[1] = 0.0f;
#pragma unroll
                    for (int m = 0; m < 5; ++m) PKFMA(lc2, x2p[m], Wlcp[m]);
                    lcp[(t - 1) * 3 + sub] = lc2[0] + lc2[1];
                }
            }
            const float pold = pos;           // inp(t) uses pos_{t-1}
            pos = fmaf(0.1f, spd, pold);
            if (j == 0) tj0 = pos; else if (j == 1) tj1 = pos;
            else if (j == 2) tj2 = pos; else tj3 = pos;
            posp[0] = pold;

            // ---- B: z(t) join: zKx + kd*pos_old + zA + zB ----
            f32x2 z01 = zKx01, z23 = zKx23;
            PKFMA_LO(z01, kd01, posp);
            PKFMA_LO(z23, kd23, posp);
            z01 = (z01 + zA01) + zB01;
            z23 = (z23 + zA23) + zB23;

            // ---- C: cell update ----
            float ig = frcp(1.0f + fexp2(z01[0]));
            float fg = frcp(1.0f + fexp2(z01[1]));
            float gg = 1.0f - 2.0f * frcp(fexp2(z23[0]) + 1.0f);
            float og = frcp(1.0f + fexp2(z23[1]));
            c = fmaf(fg, c, ig * gg);
            float th = 1.0f - 2.0f * frcp(fexp2(2.8853900817779268f * c) + 1.0f);
            hnew = og * th;

            // ---- D: h exchange (write + issue reads) ----
            h_lds[grp][sub] = hnew;
#pragma unroll
            for (int q = 0; q < 5; ++q) {
                float4 v = ((const float4*)&h_lds[grp][0])[q];
                hrp[2*q][0]   = v.x; hrp[2*q][1]   = v.y;
                hrp[2*q+1][0] = v.z; hrp[2*q+1][1] = v.w;
            }

            // ---- X: K-dot for t+1 from registers (covers h-read latency),
            //         then refill the slot with x_{t+3} ----
            {
                float4 u0 = xq[(j + 1) & 1][0];
                float4 u1 = xq[(j + 1) & 1][1];
                float4 u2 = xq[(j + 1) & 1][2];
                f32x2 xp[6];
                xp[0][0]=u0.x; xp[0][1]=u0.y; xp[1][0]=u0.z; xp[1][1]=u0.w;
                xp[2][0]=u1.x; xp[2][1]=u1.y; xp[3][0]=u1.z; xp[3][1]=u1.w;
                xp[4][0]=u2.x; xp[4][1]=u2.y; xp[5][0]=u2.z; xp[5][1]=u2.w;
                zKx01 = bz01; zKx23 = bz23;
#pragma unroll
                for (int q = 0; q < 6; ++q) {
                    PKFMA_LO(zKx01, K01[2*q],   xp[q]);
                    PKFMA_LO(zKx23, K23[2*q],   xp[q]);
                    PKFMA_HI(zKx01, K01[2*q+1], xp[q]);
                    PKFMA_HI(zKx23, K23[2*q+1], xp[q]);
                }
                int tt = t + 3; if (tt > NT - 1) tt = NT - 1;
#pragma unroll
                for (int q = 0; q < 3; ++q)
                    xq[(j + 1) & 1][q] = xg[tt * 3 + q];
            }

            // ---- E: head part 1 + x2 exchange (read covered by F) ----
            f32x2 xm2; xm2[0] = b2s; xm2[1] = 0.0f;
#pragma unroll
            for (int u = 0; u < 10; ++u) PKFMA(xm2, hrp[u], W2p[u]);
            float xm = fmaxf(xm2[0] + xm2[1], 0.0f);
            if (sub < 10) x2_lds[grp][sub] = xm;
            {
                float4 a = ((const float4*)&x2_lds[grp][0])[0];
                float4 b = ((const float4*)&x2_lds[grp][0])[1];
                float2 e = *((const float2*)&x2_lds[grp][8]);
                x2p[0][0]=a.x; x2p[0][1]=a.y; x2p[1][0]=a.z; x2p[1][1]=a.w;
                x2p[2][0]=b.x; x2p[2][1]=b.y; x2p[3][0]=b.z; x2p[3][1]=b.w;
                x2p[4][0]=e.x; x2p[4][1]=e.y;
            }

            // ---- F: R-dots for t+1 ----
            PKMUL_LO(zA01, R01[0], hrp[0]);
            PKMUL_LO(zA23, R23[0], hrp[0]);
            PKFMA_HI(zA01, R01[1], hrp[0]);
            PKFMA_HI(zA23, R23[1], hrp[0]);
#pragma unroll
            for (int q = 1; q < 5; ++q) {
                PKFMA_LO(zA01, R01[2*q],   hrp[q]);
                PKFMA_LO(zA23, R23[2*q],   hrp[q]);
                PKFMA_HI(zA01, R01[2*q+1], hrp[q]);
                PKFMA_HI(zA23, R23[2*q+1], hrp[q]);
            }
            PKMUL_LO(zB01, R01[10], hrp[5]);
            PKMUL_LO(zB23, R23[10], hrp[5]);
            PKFMA_HI(zB01, R01[11], hrp[5]);
            PKFMA_HI(zB23, R23[11], hrp[5]);
#pragma unroll
            for (int q = 6; q < 10; ++q) {
                PKFMA_LO(zB01, R01[2*q],   hrp[q]);
                PKFMA_LO(zB23, R23[2*q],   hrp[q]);
                PKFMA_HI(zB01, R01[2*q+1], hrp[q]);
                PKFMA_HI(zB23, R23[2*q+1], hrp[q]);
            }
        }

        // traj output for tb..tb+3, one float4 store (lane 0 of each group)
        if (active && sub == 0) {
            float4 tv; tv.x = tj0; tv.y = tj1; tv.z = tj2; tv.w = tj3;
            *(float4*)&trajp[tb] = tv;
        }
    }

    // ---- epilogue: finish head for step NT-1 (x2p = x2(NT-1)) ----
    {
        float a0 = b1[0], a1 = 0.0f;
#pragma unroll
        for (int m = 0; m < 5; ++m) {
            a0 = fmaf(x2p[m][0], W1[2*m],   a0);
            a1 = fmaf(x2p[m][1], W1[2*m+1], a1);
        }
        float accr = a0 + a1;
        spd = fmaf(0.1f, fmaf(10.0f, accr, -6.0f), spd);
        if (active && sub < 3) {
            f32x2 lc2; lc2[0] = blcs; lc2[1] = 0.0f;
#pragma unroll
            for (int m = 0; m < 5; ++m) PKFMA(lc2, x2p[m], Wlcp[m]);
            lcp[(NT - 1) * 3 + sub] = lc2[0] + lc2[1];
        }
    }

    if (active) {
        float* spdf = out + (size_t)NVEH * NT * 4;
        float* hf   = spdf + NVEH;
        float* cf   = hf + (size_t)NVEH * UNITS;
        if (sub == 0) spdf[veh] = spd;
        hf[(size_t)veh * UNITS + sub] = hnew;
        cf[(size_t)veh * UNITS + sub] = c;
    }
}

extern "C" void kernel_launch(void* const* d_in, const int* in_sizes, int n_in,
                              void* d_out, int out_size, void* d_ws, size_t ws_size,
                              hipStream_t stream) {
    const float* x    = (const float*)d_in[0];
    const float* st0  = (const float*)d_in[1];
    const float* hs   = (const float*)d_in[2];
    const float* K    = (const float*)d_in[3];
    const float* R    = (const float*)d_in[4];
    const float* bias = (const float*)d_in[5];
    const float* W2   = (const float*)d_in[6];
    const float* b2   = (const float*)d_in[7];
    const float* Wlc  = (const float*)d_in[8];
    const float* blc  = (const float*)d_in[9];
    const float* W1   = (const float*)d_in[10];
    const float* b1   = (const float*)d_in[11];
    float* out = (float*)d_out;

    dim3 grid((NVEH + 2) / 3);   // 1366 blocks, 3 vehicles each
    dim3 block(64);
    hipLaunchKernelGGL(rnncf_kernel, grid, block, 0, stream,
                       x, st0, hs, K, R, bias, W2, b2, Wlc, blc, W1, b1, out);
}

// Round 10
// 800.868 us; speedup vs baseline: 1.4590x; 1.2548x over previous
//
#include <hip/hip_runtime.h>
#include <cstdint>

#define NVEH  4096
#define NT    1024
#define INW   12
#define UNITS 20

#define PIN(v)  asm volatile("" : "+v"(v))

__device__ __forceinline__ float fexp2(float x) { return __builtin_amdgcn_exp2f(x); }
__device__ __forceinline__ float frcp(float x)  { return __builtin_amdgcn_rcpf(x); }

// async global -> LDS, 16B per active lane, dest = uniform base + lane*16
__device__ __forceinline__ void gload_lds16(const float* g, float* l) {
    __builtin_amdgcn_global_load_lds(
        (const __attribute__((address_space(1))) unsigned int*)g,
        (__attribute__((address_space(3))) unsigned int*)l,
        16, 0, 0);
}

// Findings baked in: v_pk_fma_f32 is 4cy on gfx950 (no gain over 2 scalar
// fma) -> ALL math is plain scalar fmaf, compiler-scheduled, no inline-asm
// movs. 2048 blocks x 2 vehicles -> every SIMD holds exactly 2 waves; wall
// = 2*issue + dual-stall with no solo-paced stragglers. Math folds (K-fold,
// kd, prescaled gates, deferred head, r7 rotation) all verified in r3/r7.
__global__ __attribute__((amdgpu_waves_per_eu(2, 2))) __launch_bounds__(64)
void rnncf_kernel(const float* __restrict__ x,          // (NVEH, NT, 12)
                  const float* __restrict__ init_state, // (NVEH, 2)
                  const float* __restrict__ hs,         // (2, NVEH, 20)
                  const float* __restrict__ K,          // (12, 80)
                  const float* __restrict__ R,          // (20, 80)
                  const float* __restrict__ bias,       // (80)
                  const float* __restrict__ W2,         // (20, 10)
                  const float* __restrict__ b2,         // (10)
                  const float* __restrict__ Wlc,        // (10, 3)
                  const float* __restrict__ blc,        // (3)
                  const float* __restrict__ W1,         // (10, 1)
                  const float* __restrict__ b1,         // (1)
                  float* __restrict__ out)
{
    const int lane = threadIdx.x;
    const int grp  = lane / 20;     // 0..1 = vehicle slot, 2..3 idle
    const int sub  = lane % 20;     // unit index / head index
    const int veh  = blockIdx.x * 2 + grp;
    const bool active = (grp < 2);  // NVEH = 2*2048 exactly, no tail
    const int vs = active ? veh : 0;

    __shared__ __align__(16) float x_lds[8][2][12];   // depth-8 x FIFO, 96B/slot
    __shared__ __align__(16) float h_lds[4][20];      // rows 2,3 = idle-group junk
    __shared__ __align__(16) float x2_lds[4][12];

    // ---- folded scalar weights: input coefs AND gate exp2 scale baked in
    // (r4/r7-verified). zKx = bz + sum K''*x_raw is pos-free; pos couples
    // via one kd*pold fma at join.
    const float L2E = 1.4426950408889634f;
    float Kf[4][12], Rf[4][20], bzf[4], kdf[4];
#pragma unroll
    for (int g = 0; g < 4; ++g) {
        const float s = (g == 2) ? (2.0f * L2E) : (-L2E);   // i,f,o: -L2E; g: +2L2E
        bzf[g] = s * bias[g * 20 + sub];
#pragma unroll
        for (int k = 0; k < 12; ++k) {
            float ck = (k < 3) ? 0.01f : (k < 6) ? -0.01f : 0.025f;
            Kf[g][k] = s * ck * K[k * 80 + g * 20 + sub];
        }
        float a = 0.0f;
        for (int k = 0; k < 6; ++k) {
            float sgn = (k < 3) ? -0.01f : 0.01f;
            a += sgn * K[k * 80 + g * 20 + sub];
        }
        kdf[g] = s * a;
#pragma unroll
        for (int k = 0; k < 20; ++k)
            Rf[g][k] = s * R[k * 80 + g * 20 + sub];
    }
    const int mh = (sub < 10) ? sub : 9;
    float W2c[20];
#pragma unroll
    for (int u = 0; u < 20; ++u) W2c[u] = W2[u * 10 + mh];
    float b2s = b2[mh];
    const int jl = (sub < 3) ? sub : 0;
    float Wlcc[10];
#pragma unroll
    for (int m = 0; m < 10; ++m) Wlcc[m] = Wlc[m * 3 + jl];
    float blcs = blc[jl];
#pragma unroll
    for (int g = 0; g < 4; ++g) {
        PIN(bzf[g]); PIN(kdf[g]);
#pragma unroll
        for (int k = 0; k < 12; ++k) PIN(Kf[g][k]);
#pragma unroll
        for (int k = 0; k < 20; ++k) PIN(Rf[g][k]);
    }
#pragma unroll
    for (int u = 0; u < 20; ++u) PIN(W2c[u]);
#pragma unroll
    for (int m = 0; m < 10; ++m) PIN(Wlcc[m]);
    PIN(b2s); PIN(blcs);

    // ---- state ----
    float pos = init_state[vs * 2 + 0];
    float spd = init_state[vs * 2 + 1];
    float c   = hs[(size_t)NVEH * UNITS + (size_t)vs * UNITS + sub];
    float hnew = hs[(size_t)vs * UNITS + sub];

    // ---- x FIFO: lanes 0..5 stage 16B/step (2 vehicles x 3 segs) ----
    const bool stg = (lane < 6);
    int sveh = blockIdx.x * 2 + lane / 3;
    if (sveh > NVEH - 1) sveh = NVEH - 1;
    const float* sgp = x + (size_t)sveh * NT * INW + (lane % 3) * 4;
    if (stg) {
#pragma unroll
        for (int t0 = 0; t0 < 8; ++t0)
            gload_lds16(sgp + (size_t)t0 * INW, &x_lds[t0][0][0]);
    }

    // ---- initial h exchange ----
    h_lds[grp][sub] = hnew;
    __builtin_amdgcn_wave_barrier();
    float hr[20];
#pragma unroll
    for (int q = 0; q < 5; ++q) {
        float4 v = ((const float4*)&h_lds[grp][0])[q];
        hr[4*q+0] = v.x; hr[4*q+1] = v.y; hr[4*q+2] = v.z; hr[4*q+3] = v.w;
    }
    __builtin_amdgcn_wave_barrier();

    // ---- prologue: zKx(0) from slot 0, zA/zB(0) from h0 ----
    asm volatile("s_waitcnt vmcnt(7)" ::: "memory");   // slot 0 resident
    float zKx[4], zA[4], zB[4];
    {
        float xr[12];
#pragma unroll
        for (int q = 0; q < 3; ++q) {
            float4 v = ((const float4*)&x_lds[0][grp][0])[q];
            xr[4*q+0] = v.x; xr[4*q+1] = v.y; xr[4*q+2] = v.z; xr[4*q+3] = v.w;
        }
#pragma unroll
        for (int g = 0; g < 4; ++g) {
            float zk = bzf[g];
#pragma unroll
            for (int k = 0; k < 12; ++k) zk = fmaf(Kf[g][k], xr[k], zk);
            zKx[g] = zk;
        }
    }
#pragma unroll
    for (int g = 0; g < 4; ++g) {
        float a = Rf[g][0] * hr[0];
#pragma unroll
        for (int k = 1; k < 10; ++k) a = fmaf(Rf[g][k], hr[k], a);
        zA[g] = a;
        float b = Rf[g][10] * hr[10];
#pragma unroll
        for (int k = 11; k < 20; ++k) b = fmaf(Rf[g][k], hr[k], b);
        zB[g] = b;
    }

    float x2r[10];         // x2(t-1), carried; step 0 guarded
#pragma unroll
    for (int m = 0; m < 10; ++m) x2r[m] = 0.0f;

    float* trajp = out + (size_t)vs * NT;
    float* lcp   = out + (size_t)NVEH * NT + (size_t)vs * NT * 3;

    for (int tb = 0; tb < NT; tb += 4) {
        // rotated body reads x slots tb+1..tb+4 -> drain oldest: vmcnt(3).
        asm volatile("s_waitcnt vmcnt(3)" ::: "memory");

#pragma unroll
        for (int j = 0; j < 4; ++j) {
            const int t = tb + j;

            // ---- A: head finish acc(t-1)->spd_t; pos update ----
            if (t > 0) {
                float a0 = b1[0], a1 = 0.0f;
#pragma unroll
                for (int m = 0; m < 5; ++m) {
                    a0 = fmaf(x2r[2*m],     W1[2*m],     a0);
                    a1 = fmaf(x2r[2*m + 1], W1[2*m + 1], a1);
                }
                float accr = a0 + a1;
                spd = fmaf(0.1f, fmaf(10.0f, accr, -6.0f), spd);
                if (active && sub < 3) {
                    float l0 = blcs, l1 = 0.0f;
#pragma unroll
                    for (int m = 0; m < 5; ++m) {
                        l0 = fmaf(x2r[2*m],     Wlcc[2*m],     l0);
                        l1 = fmaf(x2r[2*m + 1], Wlcc[2*m + 1], l1);
                    }
                    lcp[(t - 1) * 3 + sub] = l0 + l1;
                }
            }
            const float pold = pos;           // inp(t) uses pos_{t-1}
            pos = fmaf(0.1f, spd, pold);
            if (active && sub == 0) trajp[t] = pos;

            // ---- B: z(t) join: (zKx + kd*pold + zA) + zB ----
            float z0 = fmaf(kdf[0], pold, zKx[0]);
            float z1 = fmaf(kdf[1], pold, zKx[1]);
            float z2 = fmaf(kdf[2], pold, zKx[2]);
            float z3 = fmaf(kdf[3], pold, zKx[3]);
            z0 = (z0 + zA[0]) + zB[0];
            z1 = (z1 + zA[1]) + zB[1];
            z2 = (z2 + zA[2]) + zB[2];
            z3 = (z3 + zA[3]) + zB[3];

            // ---- C: cell update (weights pre-scaled: exp2 args ready) ----
            float ig = frcp(1.0f + fexp2(z0));
            float fg = frcp(1.0f + fexp2(z1));
            float gg = 1.0f - 2.0f * frcp(fexp2(z2) + 1.0f);
            float og = frcp(1.0f + fexp2(z3));
            c = fmaf(fg, c, ig * gg);
            float th = 1.0f - 2.0f * frcp(fexp2(2.8853900817779268f * c) + 1.0f);
            hnew = og * th;

            // ---- D: h exchange ----
            h_lds[grp][sub] = hnew;
#pragma unroll
            for (int q = 0; q < 5; ++q) {
                float4 v = ((const float4*)&h_lds[grp][0])[q];
                hr[4*q+0] = v.x; hr[4*q+1] = v.y; hr[4*q+2] = v.z; hr[4*q+3] = v.w;
            }

            // ---- G: x-read + K-dot for t+1 (independent filler) ----
            {
                int tn = t + 1; if (tn > NT - 1) tn = NT - 1;
                float xr[12];
#pragma unroll
                for (int q = 0; q < 3; ++q) {
                    float4 v = ((const float4*)&x_lds[tn & 7][grp][0])[q];
                    xr[4*q+0] = v.x; xr[4*q+1] = v.y; xr[4*q+2] = v.z; xr[4*q+3] = v.w;
                }
#pragma unroll
                for (int g = 0; g < 4; ++g) {
                    float zk = bzf[g];
#pragma unroll
                    for (int k = 0; k < 12; ++k) zk = fmaf(Kf[g][k], xr[k], zk);
                    zKx[g] = zk;
                }
            }

            // ---- E: head part 1 + x2 exchange ----
            {
                float e0 = b2s, e1 = 0.0f;
#pragma unroll
                for (int u = 0; u < 10; ++u) {
                    e0 = fmaf(hr[2*u],     W2c[2*u],     e0);
                    e1 = fmaf(hr[2*u + 1], W2c[2*u + 1], e1);
                }
                float xm = fmaxf(e0 + e1, 0.0f);
                if (sub < 10) x2_lds[grp][sub] = xm;
                float4 a = ((const float4*)&x2_lds[grp][0])[0];
                float4 b = ((const float4*)&x2_lds[grp][0])[1];
                float2 e = *((const float2*)&x2_lds[grp][8]);
                x2r[0]=a.x; x2r[1]=a.y; x2r[2]=a.z; x2r[3]=a.w;
                x2r[4]=b.x; x2r[5]=b.y; x2r[6]=b.z; x2r[7]=b.w;
                x2r[8]=e.x; x2r[9]=e.y;
            }

            // ---- F: R-dots for t+1 ----
#pragma unroll
            for (int g = 0; g < 4; ++g) {
                float a = Rf[g][0] * hr[0];
#pragma unroll
                for (int k = 1; k < 10; ++k) a = fmaf(Rf[g][k], hr[k], a);
                zA[g] = a;
                float b = Rf[g][10] * hr[10];
#pragma unroll
                for (int k = 11; k < 20; ++k) b = fmaf(Rf[g][k], hr[k], b);
                zB[g] = b;
            }
        }

        // issue loads for steps tb+8 .. tb+11 into the slots just consumed
        if (stg) {
#pragma unroll
            for (int j = 0; j < 4; ++j) {
                int tt = tb + 8 + j; if (tt > NT - 1) tt = NT - 1;
                gload_lds16(sgp + (size_t)tt * INW, &x_lds[(tb + j) & 7][0][0]);
            }
        }
    }

    // ---- epilogue: finish head for step NT-1 (x2r = x2(NT-1)) ----
    {
        float a0 = b1[0], a1 = 0.0f;
#pragma unroll
        for (int m = 0; m < 5; ++m) {
            a0 = fmaf(x2r[2*m],     W1[2*m],     a0);
            a1 = fmaf(x2r[2*m + 1], W1[2*m + 1], a1);
        }
        float accr = a0 + a1;
        spd = fmaf(0.1f, fmaf(10.0f, accr, -6.0f), spd);
        if (active && sub < 3) {
            float l0 = blcs, l1 = 0.0f;
#pragma unroll
            for (int m = 0; m < 5; ++m) {
                l0 = fmaf(x2r[2*m],     Wlcc[2*m],     l0);
                l1 = fmaf(x2r[2*m + 1], Wlcc[2*m + 1], l1);
            }
            lcp[(NT - 1) * 3 + sub] = l0 + l1;
        }
    }

    if (active) {
        float* spdf = out + (size_t)NVEH * NT * 4;
        float* hf   = spdf + NVEH;
        float* cf   = hf + (size_t)NVEH * UNITS;
        if (sub == 0) spdf[veh] = spd;
        hf[(size_t)veh * UNITS + sub] = hnew;
        cf[(size_t)veh * UNITS + sub] = c;
    }
}

extern "C" void kernel_launch(void* const* d_in, const int* in_sizes, int n_in,
                              void* d_out, int out_size, void* d_ws, size_t ws_size,
                              hipStream_t stream) {
    const float* x    = (const float*)d_in[0];
    const float* st0  = (const float*)d_in[1];
    const float* hs   = (const float*)d_in[2];
    const float* K    = (const float*)d_in[3];
    const float* R    = (const float*)d_in[4];
    const float* bias = (const float*)d_in[5];
    const float* W2   = (const float*)d_in[6];
    const float* b2   = (const float*)d_in[7];
    const float* Wlc  = (const float*)d_in[8];
    const float* blc  = (const float*)d_in[9];
    const float* W1   = (const float*)d_in[10];
    const float* b1   = (const float*)d_in[11];
    float* out = (float*)d_out;

    dim3 grid(NVEH / 2);   // 2048 blocks, 2 vehicles each: uniform 2 waves/SIMD
    dim3 block(64);
    hipLaunchKernelGGL(rnncf_kernel, grid, block, 0, stream,
                       x, st0, hs, K, R, bias, W2, b2, Wlc, blc, W1, b1, out);
}